// Round 12
// baseline (142.232 us; speedup 1.0000x reference)
//
#include <hip/hip_runtime.h>
#include <stdint.h>

typedef __attribute__((ext_vector_type(4))) float f32x4;
typedef __attribute__((ext_vector_type(8))) short short8;
typedef __attribute__((ext_vector_type(4))) short short4v;
typedef __attribute__((ext_vector_type(2))) unsigned uint2v;

__device__ __forceinline__ short f2bf(float f) {
    union { float f; unsigned u; } x; x.f = f;
    return (short)((x.u + 0x7fffu + ((x.u >> 16) & 1u)) >> 16);
}

__device__ __forceinline__ unsigned cvt_pk_bf16(float lo, float hi) {
    unsigned r;
    asm("v_cvt_pk_bf16_f32 %0, %1, %2" : "=v"(r) : "v"(lo), "v"(hi));
    return r;
}

__device__ __forceinline__ float fexp2(float x) {
#if __has_builtin(__builtin_amdgcn_exp2f)
    return __builtin_amdgcn_exp2f(x);
#else
    return exp2f(x);
#endif
}

#define MFMA16(a, b, c) __builtin_amdgcn_mfma_f32_16x16x32_bf16((a), (b), (c), 0, 0, 0)

__device__ __forceinline__ void gload16(const void* g, void* l) {
    __builtin_amdgcn_global_load_lds((const __attribute__((address_space(1))) void*)g,
                                     (__attribute__((address_space(3))) void*)l, 16, 0, 0);
}

// all three f32->bf16 casts in one launch
__global__ __launch_bounds__(256) void cast_all(const float* __restrict__ h,
                                                const float* __restrict__ wq,
                                                const float* __restrict__ wo,
                                                short* __restrict__ hb,
                                                short* __restrict__ wqb,
                                                short* __restrict__ wob) {
    int i = blockIdx.x * 256 + threadIdx.x;  // 1048576 chunks of 8
    const float* s;
    short* d;
    int j;
    if (i < 524288) { s = h; d = hb; j = i; }
    else if (i < 917504) { s = wq; d = wqb; j = i - 524288; }
    else { s = wo; d = wob; j = i - 917504; }
    float4 a = ((const float4*)s)[j * 2];
    float4 b = ((const float4*)s)[j * 2 + 1];
    short8 o;
    o[0] = f2bf(a.x); o[1] = f2bf(a.y); o[2] = f2bf(a.z); o[3] = f2bf(a.w);
    o[4] = f2bf(b.x); o[5] = f2bf(b.y); o[6] = f2bf(b.z); o[7] = f2bf(b.w);
    ((short8*)d)[j] = o;
}

// ------------------- 8-phase 256x256 GEMM (C = A * B^T) -------------------
template <int OUT_BF16, int QSCALE>
__global__ __launch_bounds__(512, 2) void gemm8p(const short* __restrict__ A,
                                                 const short* __restrict__ B,
                                                 void* __restrict__ Cout,
                                                 int M, int N, int K) {
    __shared__ short lds[2][4][8192];  // 128 KB
    const int t = threadIdx.x;
    const int l = t & 63, w = t >> 6;
    const int lr = l & 15, lg = l >> 4;
    const int wr = w >> 2, wc = w & 3;
    const int m0 = blockIdx.y * 256, n0 = blockIdx.x * 256;
    const int nt = K >> 6, nh = nt << 2;

    const int sr0 = t >> 2;
    const int scc = ((t & 3) ^ ((sr0 >> 1) & 3)) * 8;
    const short* As0 = A + (size_t)(m0 + sr0) * K + scc;
    const short* As1 = A + (size_t)(m0 + sr0 + 128) * K + scc;
    const short* Bs0 = B + (size_t)(n0 + sr0) * K + scc;
    const short* Bs1 = B + (size_t)(n0 + sr0 + 128) * K + scc;
    short* ldsb = &lds[0][0][0];

    auto stageH = [&](int H) {
        int Tp = H >> 2, pos = H & 3;
        int kb = Tp * 64 + ((pos <= 1) ? 32 : 0);
        short* dst = ldsb + ((Tp & 1) * 4 + pos) * 8192 + t * 8;
        if (pos & 1) {
            gload16(As0 + kb, dst);
            gload16(As1 + kb, dst + 4096);
        } else {
            gload16(Bs0 + kb, dst);
            gload16(Bs1 + kb, dst + 4096);
        }
    };

    int aoff[8], boff[4];
    #pragma unroll
    for (int mi = 0; mi < 8; ++mi) {
        int row = wr * 128 + mi * 16 + lr;
        aoff[mi] = row * 32 + (lg ^ ((row >> 1) & 3)) * 8;
    }
    #pragma unroll
    for (int ni = 0; ni < 4; ++ni) {
        int row = wc * 64 + ni * 16 + lr;
        boff[ni] = row * 32 + (lg ^ ((row >> 1) & 3)) * 8;
    }

    f32x4 acc[8][4] = {};

    for (int H = 0; H < 7; ++H) stageH(H);
    asm volatile("s_waitcnt vmcnt(6)" ::: "memory");
    __builtin_amdgcn_s_barrier();

    for (int T = 0; T < nt; ++T) {
        const short* rbase = ldsb + (T & 1) * 32768;
        const short* B1b = rbase;
        const short* A1b = rbase + 8192;
        const short* B0b = rbase + 16384;
        const short* A0b = rbase + 24576;
        const int Hs = (T << 2) + 7;
        short8 a[4], b[4];

        // ---- phase 0: k[32:64), m0-3 ----
        #pragma unroll
        for (int i = 0; i < 4; ++i) a[i] = *(const short8*)(A1b + aoff[i]);
        #pragma unroll
        for (int i = 0; i < 4; ++i) b[i] = *(const short8*)(B1b + boff[i]);
        if (Hs < nh) stageH(Hs);
        __builtin_amdgcn_sched_barrier(0);
        __builtin_amdgcn_s_barrier();
        asm volatile("s_waitcnt lgkmcnt(0)" ::: "memory");
        __builtin_amdgcn_sched_barrier(0);
        __builtin_amdgcn_s_setprio(1);
        #pragma unroll
        for (int mi = 0; mi < 4; ++mi)
            #pragma unroll
            for (int ni = 0; ni < 4; ++ni)
                acc[mi][ni] = MFMA16(a[mi], b[ni], acc[mi][ni]);
        __builtin_amdgcn_s_setprio(0);
        __builtin_amdgcn_sched_barrier(0);
        __builtin_amdgcn_s_barrier();

        // ---- phase 1: k[32:64), m4-7 ----
        #pragma unroll
        for (int i = 0; i < 4; ++i) a[i] = *(const short8*)(A1b + aoff[4 + i]);
        if (Hs + 1 < nh) stageH(Hs + 1);
        __builtin_amdgcn_sched_barrier(0);
        __builtin_amdgcn_s_barrier();
        asm volatile("s_waitcnt lgkmcnt(0)" ::: "memory");
        __builtin_amdgcn_sched_barrier(0);
        __builtin_amdgcn_s_setprio(1);
        #pragma unroll
        for (int mi = 0; mi < 4; ++mi)
            #pragma unroll
            for (int ni = 0; ni < 4; ++ni)
                acc[4 + mi][ni] = MFMA16(a[mi], b[ni], acc[4 + mi][ni]);
        __builtin_amdgcn_s_setprio(0);
        __builtin_amdgcn_sched_barrier(0);
        __builtin_amdgcn_s_barrier();

        // ---- phase 2: k[0:32), m0-3 ----
        #pragma unroll
        for (int i = 0; i < 4; ++i) a[i] = *(const short8*)(A0b + aoff[i]);
        #pragma unroll
        for (int i = 0; i < 4; ++i) b[i] = *(const short8*)(B0b + boff[i]);
        if (Hs + 2 < nh) stageH(Hs + 2);
        __builtin_amdgcn_sched_barrier(0);
        __builtin_amdgcn_s_barrier();
        asm volatile("s_waitcnt lgkmcnt(0)" ::: "memory");
        __builtin_amdgcn_sched_barrier(0);
        __builtin_amdgcn_s_setprio(1);
        #pragma unroll
        for (int mi = 0; mi < 4; ++mi)
            #pragma unroll
            for (int ni = 0; ni < 4; ++ni)
                acc[mi][ni] = MFMA16(a[mi], b[ni], acc[mi][ni]);
        __builtin_amdgcn_s_setprio(0);
        __builtin_amdgcn_sched_barrier(0);
        __builtin_amdgcn_s_barrier();

        // ---- phase 3: k[0:32), m4-7 ----
        #pragma unroll
        for (int i = 0; i < 4; ++i) a[i] = *(const short8*)(A0b + aoff[4 + i]);
        if (Hs + 3 < nh) stageH(Hs + 3);
        __builtin_amdgcn_sched_barrier(0);
        __builtin_amdgcn_s_barrier();
        asm volatile("s_waitcnt lgkmcnt(0)" ::: "memory");
        __builtin_amdgcn_sched_barrier(0);
        __builtin_amdgcn_s_setprio(1);
        #pragma unroll
        for (int mi = 0; mi < 4; ++mi)
            #pragma unroll
            for (int ni = 0; ni < 4; ++ni)
                acc[4 + mi][ni] = MFMA16(a[mi], b[ni], acc[4 + mi][ni]);
        __builtin_amdgcn_s_setprio(0);
        if (T < nt - 2) {
            asm volatile("s_waitcnt vmcnt(6)" ::: "memory");
        } else if (T == nt - 2) {
            asm volatile("s_waitcnt vmcnt(0)" ::: "memory");
        }
        __builtin_amdgcn_sched_barrier(0);
        __builtin_amdgcn_s_barrier();
    }

    const float qs = (QSCALE && n0 < 1024) ? 1.4426950408889634f : 1.0f;
    #pragma unroll
    for (int mi = 0; mi < 8; ++mi)
        #pragma unroll
        for (int ni = 0; ni < 4; ++ni)
            #pragma unroll
            for (int rr = 0; rr < 4; ++rr) {
                int mm = m0 + wr * 128 + mi * 16 + lg * 4 + rr;
                int nn = n0 + wc * 64 + ni * 16 + lr;
                float v = acc[mi][ni][rr] * qs;
                if (OUT_BF16) ((short*)Cout)[(size_t)mm * N + nn] = f2bf(v);
                else ((float*)Cout)[(size_t)mm * N + nn] = v;
            }
}

// C[M,N] = A[M,K] * B[N,K]^T, bf16 in, fp32 accum (m97 structure) — for gemm2.
template <int OUT_BF16, int QSCALE>
__global__ __launch_bounds__(256) void gemm_bt(const short* __restrict__ A,
                                               const short* __restrict__ B,
                                               void* __restrict__ Cout,
                                               int M, int N, int K) {
    __shared__ short sA[4096];
    __shared__ short sB[4096];
    const int t = threadIdx.x;
    const int l = t & 63, w = t >> 6;
    const int lr = l & 15, lg = l >> 4;
    const int m0 = blockIdx.y * 128, n0 = blockIdx.x * 128;
    const int wm = (w >> 1) * 64, wn = (w & 1) * 64;
    const int c0 = w * 64 + l, c1 = c0 + 256;
    const short* Ap0 = A + (size_t)(m0 + (c0 >> 2)) * K + (c0 & 3) * 8;
    const short* Ap1 = A + (size_t)(m0 + (c1 >> 2)) * K + (c1 & 3) * 8;
    const short* Bp0 = B + (size_t)(n0 + (c0 >> 2)) * K + (c0 & 3) * 8;
    const short* Bp1 = B + (size_t)(n0 + (c1 >> 2)) * K + (c1 & 3) * 8;
    short* lA0 = sA + w * 512;
    short* lA1 = sA + 2048 + w * 512;
    short* lB0 = sB + w * 512;
    short* lB1 = sB + 2048 + w * 512;
    f32x4 acc[4][4] = {};
    for (int k0 = 0; k0 < K; k0 += 32) {
        gload16(Ap0 + k0, lA0);
        gload16(Ap1 + k0, lA1);
        gload16(Bp0 + k0, lB0);
        gload16(Bp1 + k0, lB1);
        __syncthreads();
        short8 af[4], bfr[4];
        #pragma unroll
        for (int m = 0; m < 4; ++m) af[m] = *(const short8*)&sA[(wm + m * 16 + lr) * 32 + lg * 8];
        #pragma unroll
        for (int n = 0; n < 4; ++n) bfr[n] = *(const short8*)&sB[(wn + n * 16 + lr) * 32 + lg * 8];
        #pragma unroll
        for (int m = 0; m < 4; ++m)
            #pragma unroll
            for (int n = 0; n < 4; ++n)
                acc[m][n] = MFMA16(af[m], bfr[n], acc[m][n]);
        __syncthreads();
    }
    const float qs = (QSCALE && n0 < 1024) ? 1.4426950408889634f : 1.0f;
    #pragma unroll
    for (int m = 0; m < 4; ++m)
        #pragma unroll
        for (int n = 0; n < 4; ++n)
            #pragma unroll
            for (int r = 0; r < 4; ++r) {
                int mm = m0 + wm + m * 16 + lg * 4 + r;
                int nn = n0 + wn + n * 16 + lr;
                float v = acc[m][n][r] * qs;
                if (OUT_BF16) ((short*)Cout)[(size_t)mm * N + nn] = f2bf(v);
                else ((float*)Cout)[(size_t)mm * N + nn] = v;
            }
}

// V part of qkv [m, 2048 + h*64 + d] -> vt[bh][d][s]
__global__ __launch_bounds__(256) void transpose_v(const short* __restrict__ qkv,
                                                   short* __restrict__ vt) {
    __shared__ short T[64][72];
    const int t = threadIdx.x;
    const int s0 = blockIdx.x * 64, bh = blockIdx.y;
    const int b = bh >> 4, h = bh & 15;
    const int rl = t >> 2, cg = (t & 3) * 16;
    const short* src = qkv + (size_t)(b * 2048 + s0 + rl) * 3072 + 2048 + h * 64 + cg;
    *(short8*)&T[rl][cg] = *(const short8*)src;
    *(short8*)&T[rl][cg + 8] = *(const short8*)(src + 8);
    __syncthreads();
    short8 o0, o1;
    #pragma unroll
    for (int e = 0; e < 8; ++e) o0[e] = T[cg + e][rl];
    #pragma unroll
    for (int e = 0; e < 8; ++e) o1[e] = T[cg + 8 + e][rl];
    short* dst = vt + ((size_t)bh * 64 + rl) * 2048 + s0 + cg;
    *(short8*)dst = o0;
    *(short8*)(dst + 8) = o1;
}

// Flash attention, swapped-QK^T, exp2 domain. QBLK=32 per wave (2 q-col frags
// share each K/V LDS read -> ~1.7x less LDS traffic). 8 waves, q-tile 256,
// grid 256 blocks (1/CU). K/V dbuf + counted vmcnt (no cross-block TLP at 1/CU).
__global__ __launch_bounds__(512, 2) void attn_kernel(const short* __restrict__ qkv,
                                                      const short* __restrict__ vt,
                                                      const int* __restrict__ amask,
                                                      const float* __restrict__ rel_bias,
                                                      short* __restrict__ xout) {
    __shared__ float tbl[320];       // bias*log2e for j-i in [-159,159]
    __shared__ short sK[2][4096];    // dbuf [key 64][dk 64], XOR-swizzled chunks
    __shared__ short sV[2][4096];    // dbuf [d 64][key 64], XOR-swizzled chunks
    __shared__ short sP[8][32][72];  // per-wave P^T [q-local 32][key 64]
    __shared__ int mflags[32];       // per-64-key-tile all-nonzero flags
    const int t = threadIdx.x;       // 0..511
    const int l = t & 63, w = t >> 6;
    const int lr = l & 15, lg = l >> 4;
    const int qt = blockIdx.x, bh = blockIdx.y;
    const int b = bh >> 4, h = bh & 15;
    const int q0 = qt * 256 + w * 32;   // wave's 32 q-rows
    const float LOG2E = 1.4426950408889634f;

    if (t < 32) mflags[t] = ~0;
    if (t < 319) {
        int d = t - 159;
        int a = d < 0 ? -d : d;
        int fb = a < 8 ? a
                 : (a < 12 ? 8 : a < 16 ? 9 : a < 23 ? 10 : a < 32 ? 11
                    : a < 46 ? 12 : a < 64 ? 13 : a < 91 ? 14 : 15);
        int bk = (d > 0 ? 16 : 0) + fb;
        tbl[t] = rel_bias[bk * 16 + h] * LOG2E;
    }
    const float rbp = rel_bias[31 * 16 + h] * LOG2E;  // all d >= 91
    const float rbn = rel_bias[15 * 16 + h] * LOG2E;  // all d <= -91

    short8 qf[2][2];  // [qc][ds]
    #pragma unroll
    for (int qc = 0; qc < 2; ++qc)
        #pragma unroll
        for (int ds = 0; ds < 2; ++ds)
            qf[qc][ds] = *(const short8*)(qkv + (size_t)(b * 2048 + q0 + qc * 16 + lr) * 3072 +
                                          h * 64 + ds * 32 + lg * 8);

    // my 4 mask values (keys t*4 .. t*4+3), all within key-tile t>>4
    const int4 ma = ((const int4*)(amask + b * 2048))[t];

    // staging: thread t owns 16B chunk t of each buffer; row = t>>3 (0..63),
    // source col pre-swizzled by row&7 so swizzled reads see linear data.
    const int srow = t >> 3;
    const int scp = ((t & 7) ^ (srow & 7)) * 8;
    const short* kgp = qkv + (size_t)(b * 2048 + srow) * 3072 + 1024 + h * 64 + scp;
    const short* vgp = vt + ((size_t)bh * 64 + srow) * 2048 + scp;
    const int sw8 = (lr & 7) * 8;
    const int ibb = -q0 + lg * 4 - lr + 159;

    __syncthreads();  // mflags init + tbl visible; drains qf/mask vmem
    int mok = ma.x & ma.y & ma.z & ma.w;
    if (mok == 0) atomicAnd(&mflags[t >> 4], 0);
    __syncthreads();  // atomicAnd visible (raw barriers below don't drain lgkm)

    // prologue: stage tile 0 into buffer 0 (loads stay in flight)
    gload16(kgp, &sK[0][0] + t * 8);
    gload16(vgp, &sV[0][0] + t * 8);

    f32x4 o[4][2] = {};          // [dt][qc]
    float mreg[2] = {-1e30f, -1e30f}, lreg[2] = {0.f, 0.f};

    for (int kt = 0; kt < 2048; kt += 64) {
        const int cur = (kt >> 6) & 1;
        if (kt + 64 < 2048) {
            gload16(kgp + (size_t)(kt + 64) * 3072, &sK[cur ^ 1][0] + t * 8);
            gload16(vgp + kt + 64, &sV[cur ^ 1][0] + t * 8);
            asm volatile("s_waitcnt vmcnt(2)" ::: "memory");  // tile-cur landed
        } else {
            asm volatile("s_waitcnt vmcnt(0)" ::: "memory");
        }
        __builtin_amdgcn_sched_barrier(0);
        __builtin_amdgcn_s_barrier();
        __builtin_amdgcn_sched_barrier(0);

        const short* kb = &sK[cur][0];
        const short* vb = &sV[cur][0];

        // S^T = K * Q^T : lane holds q = q0+qc*16+lr, keys kt + ct*16 + lg*4 + r
        f32x4 pe[4][2];
        #pragma unroll
        for (int ct = 0; ct < 4; ++ct) {
            f32x4 z0 = {}, z1 = {};
            #pragma unroll
            for (int ds = 0; ds < 2; ++ds) {
                short8 kf = *(const short8*)&kb[(ct * 16 + lr) * 64 + ((ds * 32 + lg * 8) ^ sw8)];
                z0 = MFMA16(kf, qf[0][ds], z0);
                z1 = MFMA16(kf, qf[1][ds], z1);
            }
            pe[ct][0] = z0;
            pe[ct][1] = z1;
        }

        // bias (log2 domain); wave spans q0..q0+31
        float cb;
        if (kt >= q0 + 122) {
            cb = rbp;
        } else if (kt + 63 <= q0 - 91) {
            cb = rbn;
        } else {
            cb = 0.f;
            const int ib = kt + ibb;
            #pragma unroll
            for (int qc = 0; qc < 2; ++qc)
                #pragma unroll
                for (int ct = 0; ct < 4; ++ct)
                    #pragma unroll
                    for (int r = 0; r < 4; ++r)
                        pe[ct][qc][r] += tbl[ib - qc * 16 + ct * 16 + r];
        }

        // lane-local max per q-col (tree)
        float lmax[2];
        #pragma unroll
        for (int qc = 0; qc < 2; ++qc) {
            float t0 = fmaxf(fmaxf(pe[0][qc][0], pe[0][qc][1]), fmaxf(pe[0][qc][2], pe[0][qc][3]));
            float t1 = fmaxf(fmaxf(pe[1][qc][0], pe[1][qc][1]), fmaxf(pe[1][qc][2], pe[1][qc][3]));
            float t2 = fmaxf(fmaxf(pe[2][qc][0], pe[2][qc][1]), fmaxf(pe[2][qc][2], pe[2][qc][3]));
            float t3 = fmaxf(fmaxf(pe[3][qc][0], pe[3][qc][1]), fmaxf(pe[3][qc][2], pe[3][qc][3]));
            lmax[qc] = fmaxf(fmaxf(t0, t1), fmaxf(t2, t3));
        }
        bool need = (lmax[0] > mreg[0] - cb + 11.5f) | (lmax[1] > mreg[1] - cb + 11.5f);
        if (__any(need)) {
            #pragma unroll
            for (int qc = 0; qc < 2; ++qc) {
                float rm = fmaxf(lmax[qc], __shfl_xor(lmax[qc], 16));
                rm = fmaxf(rm, __shfl_xor(rm, 32));
                float mnew = fmaxf(mreg[qc], rm + cb);
                float alpha = fexp2(mreg[qc] - mnew);
                lreg[qc] *= alpha;
                #pragma unroll
                for (int dt = 0; dt < 4; ++dt)
                    #pragma unroll
                    for (int r = 0; r < 4; ++r)
                        o[dt][qc][r] *= alpha;
                mreg[qc] = mnew;
            }
        }
        const int tok = mflags[kt >> 6];
        #pragma unroll
        for (int qc = 0; qc < 2; ++qc) {
            const float madj = mreg[qc] - cb;
            float rs = 0.f;
            if (tok) {
                #pragma unroll
                for (int ct = 0; ct < 4; ++ct) {
                    float p[4];
                    #pragma unroll
                    for (int r = 0; r < 4; ++r) {
                        float pv = fexp2(pe[ct][qc][r] - madj);
                        p[r] = pv;
                        rs += pv;
                    }
                    uint2v pk;
                    pk[0] = cvt_pk_bf16(p[0], p[1]);
                    pk[1] = cvt_pk_bf16(p[2], p[3]);
                    *(uint2v*)&sP[w][qc * 16 + lr][ct * 16 + lg * 4] = pk;
                }
            } else {
                const int4* mp = (const int4*)(amask + b * 2048 + kt);
                #pragma unroll
                for (int ct = 0; ct < 4; ++ct) {
                    int4 cm = mp[ct * 4 + lg];
                    float p[4];
                    #pragma unroll
                    for (int r = 0; r < 4; ++r) {
                        float pv = fexp2(pe[ct][qc][r] - madj);
                        pv = ((const int*)&cm)[r] ? pv : 0.f;
                        p[r] = pv;
                        rs += pv;
                    }
                    uint2v pk;
                    pk[0] = cvt_pk_bf16(p[0], p[1]);
                    pk[1] = cvt_pk_bf16(p[2], p[3]);
                    *(uint2v*)&sP[w][qc * 16 + lr][ct * 16 + lg * 4] = pk;
                }
            }
            lreg[qc] += rs;
        }

        // O^T += V^T * P^T : each vf read feeds both q-cols
        #pragma unroll
        for (int kk = 0; kk < 2; ++kk) {
            short8 pf0 = *(const short8*)&sP[w][lr][kk * 32 + lg * 8];
            short8 pf1 = *(const short8*)&sP[w][16 + lr][kk * 32 + lg * 8];
            #pragma unroll
            for (int dt = 0; dt < 4; ++dt) {
                short8 vf = *(const short8*)&vb[(dt * 16 + lr) * 64 + ((kk * 32 + lg * 8) ^ sw8)];
                o[dt][0] = MFMA16(vf, pf0, o[dt][0]);
                o[dt][1] = MFMA16(vf, pf1, o[dt][1]);
            }
        }
        __builtin_amdgcn_sched_barrier(0);
        __builtin_amdgcn_s_barrier();   // all waves done reading buf[cur] + sP
        __builtin_amdgcn_sched_barrier(0);
    }

    #pragma unroll
    for (int qc = 0; qc < 2; ++qc) {
        float lsum = lreg[qc] + __shfl_xor(lreg[qc], 16);
        lsum += __shfl_xor(lsum, 32);
        const float inv = 1.0f / lsum;
        #pragma unroll
        for (int dt = 0; dt < 4; ++dt) {
            short4v ov;
            #pragma unroll
            for (int r = 0; r < 4; ++r) ov[r] = f2bf(o[dt][qc][r] * inv);
            *(short4v*)(xout + (size_t)(b * 2048 + q0 + qc * 16 + lr) * 1024 +
                        h * 64 + dt * 16 + lg * 4) = ov;
        }
    }
}

extern "C" void kernel_launch(void* const* d_in, const int* in_sizes, int n_in,
                              void* d_out, int out_size, void* d_ws, size_t ws_size,
                              hipStream_t stream) {
    const float* hidden = (const float*)d_in[0];
    const int* amask = (const int*)d_in[1];
    const float* w_qkv = (const float*)d_in[2];
    const float* rel_bias = (const float*)d_in[3];
    const float* w_o = (const float*)d_in[4];
    if (ws_size < 58720256) return;
    char* ws = (char*)d_ws;
    short* hidden_bf = (short*)(ws + 0);
    short* wqkv_bf   = (short*)(ws + 8388608);
    short* wo_bf     = (short*)(ws + 14680064);
    short* qkv       = (short*)(ws + 16777216);
    short* vt        = (short*)(ws + 41943040);
    short* xbuf      = (short*)(ws + 50331648);

    cast_all<<<4096, 256, 0, stream>>>(hidden, w_qkv, w_o, hidden_bf, wqkv_bf, wo_bf);
    gemm8p<1, 1><<<dim3(12, 16), 512, 0, stream>>>(hidden_bf, wqkv_bf, qkv, 4096, 3072, 1024);
    transpose_v<<<dim3(32, 32), 256, 0, stream>>>(qkv, vt);
    attn_kernel<<<dim3(8, 32), 512, 0, stream>>>(qkv, vt, amask, rel_bias, xbuf);
    gemm_bt<0, 0><<<dim3(8, 32), 256, 0, stream>>>(xbuf, wo_bf, d_out, 4096, 1024, 1024);
}

// Round 16
// 133.596 us; speedup vs baseline: 1.0646x; 1.0646x over previous
//
#include <hip/hip_runtime.h>
#include <stdint.h>

typedef __attribute__((ext_vector_type(4))) float f32x4;
typedef __attribute__((ext_vector_type(8))) short short8;
typedef __attribute__((ext_vector_type(4))) short short4v;
typedef __attribute__((ext_vector_type(2))) unsigned uint2v;

__device__ __forceinline__ short f2bf(float f) {
    union { float f; unsigned u; } x; x.f = f;
    return (short)((x.u + 0x7fffu + ((x.u >> 16) & 1u)) >> 16);
}

__device__ __forceinline__ unsigned cvt_pk_bf16(float lo, float hi) {
    unsigned r;
    asm("v_cvt_pk_bf16_f32 %0, %1, %2" : "=v"(r) : "v"(lo), "v"(hi));
    return r;
}

__device__ __forceinline__ float fexp2(float x) {
#if __has_builtin(__builtin_amdgcn_exp2f)
    return __builtin_amdgcn_exp2f(x);
#else
    return exp2f(x);
#endif
}

#define MFMA16(a, b, c) __builtin_amdgcn_mfma_f32_16x16x32_bf16((a), (b), (c), 0, 0, 0)

__device__ __forceinline__ void gload16(const void* g, void* l) {
    __builtin_amdgcn_global_load_lds((const __attribute__((address_space(1))) void*)g,
                                     (__attribute__((address_space(3))) void*)l, 16, 0, 0);
}

// all three f32->bf16 casts in one launch
__global__ __launch_bounds__(256) void cast_all(const float* __restrict__ h,
                                                const float* __restrict__ wq,
                                                const float* __restrict__ wo,
                                                short* __restrict__ hb,
                                                short* __restrict__ wqb,
                                                short* __restrict__ wob) {
    int i = blockIdx.x * 256 + threadIdx.x;  // 1048576 chunks of 8
    const float* s;
    short* d;
    int j;
    if (i < 524288) { s = h; d = hb; j = i; }
    else if (i < 917504) { s = wq; d = wqb; j = i - 524288; }
    else { s = wo; d = wob; j = i - 917504; }
    float4 a = ((const float4*)s)[j * 2];
    float4 b = ((const float4*)s)[j * 2 + 1];
    short8 o;
    o[0] = f2bf(a.x); o[1] = f2bf(a.y); o[2] = f2bf(a.z); o[3] = f2bf(a.w);
    o[4] = f2bf(b.x); o[5] = f2bf(b.y); o[6] = f2bf(b.z); o[7] = f2bf(b.w);
    ((short8*)d)[j] = o;
}

// ------------------- 8-phase 256x256 GEMM (C = A * B^T) -------------------
// QSCALE: scale cols [0,1024) by log2e. VFUSE: for n0>=2048 (V region) write
// transposed into vt[bh][d][s] instead of C (fuses the old transpose_v pass).
template <int OUT_BF16, int QSCALE, int VFUSE>
__global__ __launch_bounds__(512, 2) void gemm8p(const short* __restrict__ A,
                                                 const short* __restrict__ B,
                                                 void* __restrict__ Cout,
                                                 short* __restrict__ vt,
                                                 int M, int N, int K) {
    __shared__ short lds[2][4][8192];  // 128 KB
    const int t = threadIdx.x;
    const int l = t & 63, w = t >> 6;
    const int lr = l & 15, lg = l >> 4;
    const int wr = w >> 2, wc = w & 3;
    const int m0 = blockIdx.y * 256, n0 = blockIdx.x * 256;
    const int nt = K >> 6, nh = nt << 2;

    const int sr0 = t >> 2;
    const int scc = ((t & 3) ^ ((sr0 >> 1) & 3)) * 8;
    const short* As0 = A + (size_t)(m0 + sr0) * K + scc;
    const short* As1 = A + (size_t)(m0 + sr0 + 128) * K + scc;
    const short* Bs0 = B + (size_t)(n0 + sr0) * K + scc;
    const short* Bs1 = B + (size_t)(n0 + sr0 + 128) * K + scc;
    short* ldsb = &lds[0][0][0];

    auto stageH = [&](int H) {
        int Tp = H >> 2, pos = H & 3;
        int kb = Tp * 64 + ((pos <= 1) ? 32 : 0);
        short* dst = ldsb + ((Tp & 1) * 4 + pos) * 8192 + t * 8;
        if (pos & 1) {
            gload16(As0 + kb, dst);
            gload16(As1 + kb, dst + 4096);
        } else {
            gload16(Bs0 + kb, dst);
            gload16(Bs1 + kb, dst + 4096);
        }
    };

    int aoff[8], boff[4];
    #pragma unroll
    for (int mi = 0; mi < 8; ++mi) {
        int row = wr * 128 + mi * 16 + lr;
        aoff[mi] = row * 32 + (lg ^ ((row >> 1) & 3)) * 8;
    }
    #pragma unroll
    for (int ni = 0; ni < 4; ++ni) {
        int row = wc * 64 + ni * 16 + lr;
        boff[ni] = row * 32 + (lg ^ ((row >> 1) & 3)) * 8;
    }

    f32x4 acc[8][4] = {};

    for (int H = 0; H < 7; ++H) stageH(H);
    asm volatile("s_waitcnt vmcnt(6)" ::: "memory");
    __builtin_amdgcn_s_barrier();

    for (int T = 0; T < nt; ++T) {
        const short* rbase = ldsb + (T & 1) * 32768;
        const short* B1b = rbase;
        const short* A1b = rbase + 8192;
        const short* B0b = rbase + 16384;
        const short* A0b = rbase + 24576;
        const int Hs = (T << 2) + 7;
        short8 a[4], b[4];

        // ---- phase 0: k[32:64), m0-3 ----
        #pragma unroll
        for (int i = 0; i < 4; ++i) a[i] = *(const short8*)(A1b + aoff[i]);
        #pragma unroll
        for (int i = 0; i < 4; ++i) b[i] = *(const short8*)(B1b + boff[i]);
        if (Hs < nh) stageH(Hs);
        __builtin_amdgcn_sched_barrier(0);
        __builtin_amdgcn_s_barrier();
        asm volatile("s_waitcnt lgkmcnt(0)" ::: "memory");
        __builtin_amdgcn_sched_barrier(0);
        __builtin_amdgcn_s_setprio(1);
        #pragma unroll
        for (int mi = 0; mi < 4; ++mi)
            #pragma unroll
            for (int ni = 0; ni < 4; ++ni)
                acc[mi][ni] = MFMA16(a[mi], b[ni], acc[mi][ni]);
        __builtin_amdgcn_s_setprio(0);
        __builtin_amdgcn_sched_barrier(0);
        __builtin_amdgcn_s_barrier();

        // ---- phase 1: k[32:64), m4-7 ----
        #pragma unroll
        for (int i = 0; i < 4; ++i) a[i] = *(const short8*)(A1b + aoff[4 + i]);
        if (Hs + 1 < nh) stageH(Hs + 1);
        __builtin_amdgcn_sched_barrier(0);
        __builtin_amdgcn_s_barrier();
        asm volatile("s_waitcnt lgkmcnt(0)" ::: "memory");
        __builtin_amdgcn_sched_barrier(0);
        __builtin_amdgcn_s_setprio(1);
        #pragma unroll
        for (int mi = 0; mi < 4; ++mi)
            #pragma unroll
            for (int ni = 0; ni < 4; ++ni)
                acc[4 + mi][ni] = MFMA16(a[mi], b[ni], acc[4 + mi][ni]);
        __builtin_amdgcn_s_setprio(0);
        __builtin_amdgcn_sched_barrier(0);
        __builtin_amdgcn_s_barrier();

        // ---- phase 2: k[0:32), m0-3 ----
        #pragma unroll
        for (int i = 0; i < 4; ++i) a[i] = *(const short8*)(A0b + aoff[i]);
        #pragma unroll
        for (int i = 0; i < 4; ++i) b[i] = *(const short8*)(B0b + boff[i]);
        if (Hs + 2 < nh) stageH(Hs + 2);
        __builtin_amdgcn_sched_barrier(0);
        __builtin_amdgcn_s_barrier();
        asm volatile("s_waitcnt lgkmcnt(0)" ::: "memory");
        __builtin_amdgcn_sched_barrier(0);
        __builtin_amdgcn_s_setprio(1);
        #pragma unroll
        for (int mi = 0; mi < 4; ++mi)
            #pragma unroll
            for (int ni = 0; ni < 4; ++ni)
                acc[mi][ni] = MFMA16(a[mi], b[ni], acc[mi][ni]);
        __builtin_amdgcn_s_setprio(0);
        __builtin_amdgcn_sched_barrier(0);
        __builtin_amdgcn_s_barrier();

        // ---- phase 3: k[0:32), m4-7 ----
        #pragma unroll
        for (int i = 0; i < 4; ++i) a[i] = *(const short8*)(A0b + aoff[4 + i]);
        if (Hs + 3 < nh) stageH(Hs + 3);
        __builtin_amdgcn_sched_barrier(0);
        __builtin_amdgcn_s_barrier();
        asm volatile("s_waitcnt lgkmcnt(0)" ::: "memory");
        __builtin_amdgcn_sched_barrier(0);
        __builtin_amdgcn_s_setprio(1);
        #pragma unroll
        for (int mi = 0; mi < 4; ++mi)
            #pragma unroll
            for (int ni = 0; ni < 4; ++ni)
                acc[4 + mi][ni] = MFMA16(a[mi], b[ni], acc[4 + mi][ni]);
        __builtin_amdgcn_s_setprio(0);
        if (T < nt - 2) {
            asm volatile("s_waitcnt vmcnt(6)" ::: "memory");
        } else if (T == nt - 2) {
            asm volatile("s_waitcnt vmcnt(0)" ::: "memory");
        }
        __builtin_amdgcn_sched_barrier(0);
        __builtin_amdgcn_s_barrier();
    }

    if (VFUSE && n0 >= 2048) {
        // V region: write transposed to vt[(b*16+h)*64 + d][s], s = row index
        #pragma unroll
        for (int mi = 0; mi < 8; ++mi)
            #pragma unroll
            for (int ni = 0; ni < 4; ++ni) {
                int nn = n0 + wc * 64 + ni * 16 + lr;
                int h = (nn - 2048) >> 6, dd = (nn - 2048) & 63;
                int mm = m0 + wr * 128 + mi * 16 + lg * 4;
                int bb = mm >> 11, s = mm & 2047;
                short4v ov;
                #pragma unroll
                for (int rr = 0; rr < 4; ++rr) ov[rr] = f2bf(acc[mi][ni][rr]);
                *(short4v*)(vt + ((size_t)(bb * 16 + h) * 64 + dd) * 2048 + s) = ov;
            }
        return;
    }
    const float qs = (QSCALE && n0 < 1024) ? 1.4426950408889634f : 1.0f;
    #pragma unroll
    for (int mi = 0; mi < 8; ++mi)
        #pragma unroll
        for (int ni = 0; ni < 4; ++ni)
            #pragma unroll
            for (int rr = 0; rr < 4; ++rr) {
                int mm = m0 + wr * 128 + mi * 16 + lg * 4 + rr;
                int nn = n0 + wc * 64 + ni * 16 + lr;
                float v = acc[mi][ni][rr] * qs;
                if (OUT_BF16) ((short*)Cout)[(size_t)mm * N + nn] = f2bf(v);
                else ((float*)Cout)[(size_t)mm * N + nn] = v;
            }
}

// C[M,N] = A[M,K] * B[N,K]^T, bf16 in, fp32 accum (m97 structure) — for gemm2.
template <int OUT_BF16>
__global__ __launch_bounds__(256) void gemm_bt(const short* __restrict__ A,
                                               const short* __restrict__ B,
                                               void* __restrict__ Cout,
                                               int M, int N, int K) {
    __shared__ short sA[4096];
    __shared__ short sB[4096];
    const int t = threadIdx.x;
    const int l = t & 63, w = t >> 6;
    const int lr = l & 15, lg = l >> 4;
    const int m0 = blockIdx.y * 128, n0 = blockIdx.x * 128;
    const int wm = (w >> 1) * 64, wn = (w & 1) * 64;
    const int c0 = w * 64 + l, c1 = c0 + 256;
    const short* Ap0 = A + (size_t)(m0 + (c0 >> 2)) * K + (c0 & 3) * 8;
    const short* Ap1 = A + (size_t)(m0 + (c1 >> 2)) * K + (c1 & 3) * 8;
    const short* Bp0 = B + (size_t)(n0 + (c0 >> 2)) * K + (c0 & 3) * 8;
    const short* Bp1 = B + (size_t)(n0 + (c1 >> 2)) * K + (c1 & 3) * 8;
    short* lA0 = sA + w * 512;
    short* lA1 = sA + 2048 + w * 512;
    short* lB0 = sB + w * 512;
    short* lB1 = sB + 2048 + w * 512;
    f32x4 acc[4][4] = {};
    for (int k0 = 0; k0 < K; k0 += 32) {
        gload16(Ap0 + k0, lA0);
        gload16(Ap1 + k0, lA1);
        gload16(Bp0 + k0, lB0);
        gload16(Bp1 + k0, lB1);
        __syncthreads();
        short8 af[4], bfr[4];
        #pragma unroll
        for (int m = 0; m < 4; ++m) af[m] = *(const short8*)&sA[(wm + m * 16 + lr) * 32 + lg * 8];
        #pragma unroll
        for (int n = 0; n < 4; ++n) bfr[n] = *(const short8*)&sB[(wn + n * 16 + lr) * 32 + lg * 8];
        #pragma unroll
        for (int m = 0; m < 4; ++m)
            #pragma unroll
            for (int n = 0; n < 4; ++n)
                acc[m][n] = MFMA16(af[m], bfr[n], acc[m][n]);
        __syncthreads();
    }
    #pragma unroll
    for (int m = 0; m < 4; ++m)
        #pragma unroll
        for (int n = 0; n < 4; ++n)
            #pragma unroll
            for (int r = 0; r < 4; ++r) {
                int mm = m0 + wm + m * 16 + lg * 4 + r;
                int nn = n0 + wn + n * 16 + lr;
                float v = acc[m][n][r];
                if (OUT_BF16) ((short*)Cout)[(size_t)mm * N + nn] = f2bf(v);
                else ((float*)Cout)[(size_t)mm * N + nn] = v;
            }
}

// Flash attention, swapped-QK^T, exp2 domain. 8 waves x 16 q-rows (q-tile 128),
// single K/V LDS buffer shared by 8 waves; grid 512 blocks (2/CU, 16 waves/CU).
// (R10 exact — best measured attn structure: 64.2 us)
__global__ __launch_bounds__(512, 4) void attn_kernel(const short* __restrict__ qkv,
                                                      const short* __restrict__ vt,
                                                      const int* __restrict__ amask,
                                                      const float* __restrict__ rel_bias,
                                                      short* __restrict__ xout) {
    __shared__ float tbl[340];       // bias*log2e for j-i in [-168,168]
    __shared__ short sK[4096];       // [key 64][dk 64], XOR-swizzled chunks
    __shared__ short sV[4096];       // [d 64][key 64], XOR-swizzled chunks
    __shared__ short sP[8][16][72];  // per-wave P^T
    __shared__ int mflags[32];       // per-64-key-tile all-nonzero flags
    const int t = threadIdx.x;       // 0..511
    const int l = t & 63, w = t >> 6;
    const int lr = l & 15, lg = l >> 4;
    const int qt = blockIdx.x, bh = blockIdx.y;
    const int b = bh >> 4, h = bh & 15;
    const int q0 = qt * 128 + w * 16;
    const float LOG2E = 1.4426950408889634f;

    if (t < 32) mflags[t] = ~0;
    if (t < 337) {
        int idx = t;
        int d = idx - 168;
        int a = d < 0 ? -d : d;
        int fb = a < 8 ? a
                 : (a < 12 ? 8 : a < 16 ? 9 : a < 23 ? 10 : a < 32 ? 11
                    : a < 46 ? 12 : a < 64 ? 13 : a < 91 ? 14 : 15);
        int bk = (d > 0 ? 16 : 0) + fb;
        tbl[idx] = rel_bias[bk * 16 + h] * LOG2E;
    }
    const float rbp = rel_bias[31 * 16 + h] * LOG2E;  // d >= 91
    const float rbn = rel_bias[15 * 16 + h] * LOG2E;  // d <= -91

    short8 qf[2];
    #pragma unroll
    for (int ds = 0; ds < 2; ++ds)
        qf[ds] = *(const short8*)(qkv + (size_t)(b * 2048 + q0 + lr) * 3072 + h * 64 + ds * 32 + lg * 8);

    // my 4 mask values (keys t*4 .. t*4+3), all within key-tile t>>4
    const int4 ma = ((const int4*)(amask + b * 2048))[t];

    // staging: thread t owns 16B chunk t of sK and sV; row = t>>3 (0..63),
    // source col pre-swizzled by row&7 so swizzled reads see linear data.
    const int srow = t >> 3;
    const int scp = ((t & 7) ^ (srow & 7)) * 8;
    const short* kgp = qkv + (size_t)(b * 2048 + srow) * 3072 + 1024 + h * 64 + scp;
    const short* vgp = vt + ((size_t)bh * 64 + srow) * 2048 + scp;
    short* dK = sK + t * 8;
    short* dV = sV + t * 8;
    const int sw8 = (lr & 7) * 8;
    const int ibb = -q0 + lg * 4 - lr + 168;

    __syncthreads();  // mflags init visible
    int mok = ma.x & ma.y & ma.z & ma.w;
    if (mok == 0) atomicAnd(&mflags[t >> 4], 0);

    f32x4 o[4] = {};
    float mreg = -1e30f, lreg = 0.f;

    for (int kt = 0; kt < 2048; kt += 64) {
        gload16(kgp + (size_t)kt * 3072, dK);
        gload16(vgp + kt, dV);
        __syncthreads();  // stage drained (+ atomicAnd visible on first iter)

        // S^T = K * Q^T : lane holds q = q0+lr, keys kt + ct*16 + lg*4 + r
        f32x4 pe[4];
        #pragma unroll
        for (int ct = 0; ct < 4; ++ct) {
            f32x4 z = {};
            #pragma unroll
            for (int ds = 0; ds < 2; ++ds) {
                short8 kf = *(const short8*)&sK[(ct * 16 + lr) * 64 + ((ds * 32 + lg * 8) ^ sw8)];
                z = MFMA16(kf, qf[ds], z);
            }
            pe[ct] = z;
        }

        // bias (log2 domain)
        float cb;
        if (kt >= q0 + 106) {
            cb = rbp;
        } else if (kt + 63 <= q0 - 91) {
            cb = rbn;
        } else {
            cb = 0.f;
            const int ib = kt + ibb;
            #pragma unroll
            for (int ct = 0; ct < 4; ++ct)
                #pragma unroll
                for (int r = 0; r < 4; ++r)
                    pe[ct][r] += tbl[ib + ct * 16 + r];
        }

        // lane-local max (tree, max3-fusable)
        float t0 = fmaxf(fmaxf(pe[0][0], pe[0][1]), fmaxf(pe[0][2], pe[0][3]));
        float t1 = fmaxf(fmaxf(pe[1][0], pe[1][1]), fmaxf(pe[1][2], pe[1][3]));
        float t2 = fmaxf(fmaxf(pe[2][0], pe[2][1]), fmaxf(pe[2][2], pe[2][3]));
        float t3 = fmaxf(fmaxf(pe[3][0], pe[3][1]), fmaxf(pe[3][2], pe[3][3]));
        float lmax = fmaxf(fmaxf(t0, t1), fmaxf(t2, t3));
        if (__any(lmax > mreg - cb + 11.5f)) {
            float rm = fmaxf(lmax, __shfl_xor(lmax, 16));
            rm = fmaxf(rm, __shfl_xor(rm, 32));
            float mnew = fmaxf(mreg, rm + cb);
            float alpha = fexp2(mreg - mnew);
            lreg *= alpha;
            #pragma unroll
            for (int dt = 0; dt < 4; ++dt)
                #pragma unroll
                for (int r = 0; r < 4; ++r)
                    o[dt][r] *= alpha;
            mreg = mnew;
        }
        const float madj = mreg - cb;
        const int tok = mflags[kt >> 6];
        float rs = 0.f;
        if (tok) {
            #pragma unroll
            for (int ct = 0; ct < 4; ++ct) {
                float p[4];
                #pragma unroll
                for (int r = 0; r < 4; ++r) {
                    float pv = fexp2(pe[ct][r] - madj);
                    p[r] = pv;
                    rs += pv;
                }
                uint2v pk;
                pk[0] = cvt_pk_bf16(p[0], p[1]);
                pk[1] = cvt_pk_bf16(p[2], p[3]);
                *(uint2v*)&sP[w][lr][ct * 16 + lg * 4] = pk;
            }
        } else {
            const int4* mp = (const int4*)(amask + b * 2048 + kt);
            #pragma unroll
            for (int ct = 0; ct < 4; ++ct) {
                int4 cm = mp[ct * 4 + lg];
                float p[4];
                #pragma unroll
                for (int r = 0; r < 4; ++r) {
                    float pv = fexp2(pe[ct][r] - madj);
                    pv = ((const int*)&cm)[r] ? pv : 0.f;
                    p[r] = pv;
                    rs += pv;
                }
                uint2v pk;
                pk[0] = cvt_pk_bf16(p[0], p[1]);
                pk[1] = cvt_pk_bf16(p[2], p[3]);
                *(uint2v*)&sP[w][lr][ct * 16 + lg * 4] = pk;
            }
        }
        lreg += rs;

        // O^T += V^T * P^T
        #pragma unroll
        for (int kk = 0; kk < 2; ++kk) {
            short8 pf = *(const short8*)&sP[w][lr][kk * 32 + lg * 8];
            #pragma unroll
            for (int dt = 0; dt < 4; ++dt) {
                short8 vf = *(const short8*)&sV[(dt * 16 + lr) * 64 + ((kk * 32 + lg * 8) ^ sw8)];
                o[dt] = MFMA16(vf, pf, o[dt]);
            }
        }
        __syncthreads();  // all waves done with sK/sV before next stage
    }

    float lsum = lreg + __shfl_xor(lreg, 16);
    lsum += __shfl_xor(lsum, 32);
    const float inv = 1.0f / lsum;
    #pragma unroll
    for (int dt = 0; dt < 4; ++dt) {
        short4v ov;
        #pragma unroll
        for (int r = 0; r < 4; ++r) ov[r] = f2bf(o[dt][r] * inv);
        *(short4v*)(xout + (size_t)(b * 2048 + q0 + lr) * 1024 + h * 64 + dt * 16 + lg * 4) = ov;
    }
}

extern "C" void kernel_launch(void* const* d_in, const int* in_sizes, int n_in,
                              void* d_out, int out_size, void* d_ws, size_t ws_size,
                              hipStream_t stream) {
    const float* hidden = (const float*)d_in[0];
    const int* amask = (const int*)d_in[1];
    const float* w_qkv = (const float*)d_in[2];
    const float* rel_bias = (const float*)d_in[3];
    const float* w_o = (const float*)d_in[4];
    if (ws_size < 58720256) return;
    char* ws = (char*)d_ws;
    short* hidden_bf = (short*)(ws + 0);
    short* wqkv_bf   = (short*)(ws + 8388608);
    short* wo_bf     = (short*)(ws + 14680064);
    short* qkv       = (short*)(ws + 16777216);
    short* vt        = (short*)(ws + 41943040);
    short* xbuf      = (short*)(ws + 50331648);

    cast_all<<<4096, 256, 0, stream>>>(hidden, w_qkv, w_o, hidden_bf, wqkv_bf, wo_bf);
    gemm8p<1, 1, 1><<<dim3(12, 16), 512, 0, stream>>>(hidden_bf, wqkv_bf, qkv, vt, 4096, 3072, 1024);
    attn_kernel<<<dim3(16, 32), 512, 0, stream>>>(qkv, vt, amask, rel_bias, xbuf);
    gemm_bt<0><<<dim3(8, 32), 256, 0, stream>>>(xbuf, wo_bf, d_out, 4096, 1024, 1024);
}